// Round 1
// baseline (177.684 us; speedup 1.0000x reference)
//
#include <hip/hip_runtime.h>

// Problem constants (from reference):
//   x:       [B=16, E=64, S=32768] float32
//   indices: [B=16, E=64] int (values in [0, S/STEP))
//   out:     [B, 1, S] float32  -> flat B*S
// out[b,s] = sum_e x[b, e, s - idx[b,e]*STEP]  where idx*STEP <= s
constexpr int B = 16;
constexpr int E = 64;
constexpr int S = 32768;
constexpr int STEP = 256;
constexpr int HALF = 512;      // samples per half-tile
constexpr int GRP  = 16;       // loads in flight per thread

// Load-balanced gather with per-half-tile ACTIVE-EVENT COMPACTION.
//
// Pairing: waves 0-1 (threads 0..127) cover half-tile pr; waves 2-3 cover
// 63-pr, so per-block HBM demand is ~constant regardless of CU assignment.
//
// New in this version: expected active events for half-tile h is only h+1
// (avg 33/64). Previously all 64 events were iterated with masked clamped
// loads -> ~2x the necessary VMEM/VALU instruction stream. Now wave 0
// (resp. 1) builds a ballot-compacted list of events with te <= s_max for
// its half, sentinel-padded to a GRP multiple; consumers loop only over
// that list. HBM traffic is unchanged (masked loads were broadcast L2
// hits); instruction count drops ~40%. Summation order over surviving
// events is preserved and masked terms were exact +0.0f, so the result is
// bitwise identical (absmax stays 0).
__global__ __launch_bounds__(256)
void sparse_audio_gather(const float* __restrict__ x,
                         const int* __restrict__ idx,
                         float* __restrict__ out) {
    const int b     = blockIdx.y;
    const int pr    = blockIdx.x;                       // 0..31
    const int lo    = (threadIdx.x < 128);              // wave-uniform
    const int half  = lo ? pr : (63 - pr);
    const int local = (int)(threadIdx.x & 127);
    const int s0    = half * HALF + local * 4;          // < S always

    // Compacted per-half lists: (te, e*S) pairs + padded count.
    __shared__ int2 lst[2][E + GRP];
    __shared__ int  cnt_l[2];

    // Wave 0 builds the list for half pr, wave 1 for half 63-pr.
    if (threadIdx.x < 2 * E) {
        const int hsel = (int)(threadIdx.x >> 6);       // 0 or 1
        const int h    = hsel ? (63 - pr) : pr;
        const int lane = (int)(threadIdx.x & 63);
        const int te   = idx[b * E + lane] * STEP;
        const int smax = h * HALF + (HALF - 4);         // max s0 in this half
        const bool act = (te <= smax);
        const unsigned long long mask = __ballot(act);
        const int pos  = __popcll(mask & ((1ull << lane) - 1ull));
        const int cnt  = __popcll(mask);
        const int cntp = (cnt + GRP - 1) & ~(GRP - 1);  // pad to GRP multiple
        if (act) lst[hsel][pos] = make_int2(te, lane * S);
        // Sentinels: te huge -> off<0 on every lane -> m=0, clamped addr xb[0].
        if (lane >= cnt && lane < cntp) lst[hsel][lane] = make_int2(1 << 28, 0);
        if (lane == 0) cnt_l[hsel] = cntp;
    }
    __syncthreads();

    const float* xb = x + (size_t)b * E * S;
    const int hs  = lo ? 0 : 1;
    const int cnt = cnt_l[hs];                          // wave-uniform, %GRP==0

    float4 acc = make_float4(0.f, 0.f, 0.f, 0.f);

    // Unconditional clamped loads (address p.y + max(s0-te,0) is always in
    // [p.y, p.y + s0] subset [0, B-row end]), masked after the fact: GRP
    // loads issue back-to-back before any s_waitcnt.
    for (int i0 = 0; i0 < cnt; i0 += GRP) {
        int2   p[GRP];
        float4 v[GRP];
        float  m[GRP];
        #pragma unroll
        for (int j = 0; j < GRP; ++j) p[j] = lst[hs][i0 + j];
        #pragma unroll
        for (int j = 0; j < GRP; ++j) {
            const int off  = s0 - p[j].x;
            const int offc = off < 0 ? 0 : off;
            m[j] = off < 0 ? 0.0f : 1.0f;
            v[j] = *reinterpret_cast<const float4*>(
                       xb + (size_t)(p[j].y + offc));
        }
        #pragma unroll
        for (int j = 0; j < GRP; ++j) {
            acc.x += m[j] * v[j].x;
            acc.y += m[j] * v[j].y;
            acc.z += m[j] * v[j].z;
            acc.w += m[j] * v[j].w;
        }
    }

    *reinterpret_cast<float4*>(out + (size_t)b * S + s0) = acc;
}

extern "C" void kernel_launch(void* const* d_in, const int* in_sizes, int n_in,
                              void* d_out, int out_size, void* d_ws, size_t ws_size,
                              hipStream_t stream) {
    const float* x   = (const float*)d_in[0];
    const int*   idx = (const int*)d_in[1];
    float*       out = (float*)d_out;

    dim3 grid(S / (2 * HALF), B);   // (32, 16) — each block does 2 half-tiles
    dim3 block(256);
    sparse_audio_gather<<<grid, block, 0, stream>>>(x, idx, out);
}

// Round 3
// 171.457 us; speedup vs baseline: 1.0363x; 1.0363x over previous
//
#include <hip/hip_runtime.h>

// Problem constants (from reference):
//   x:       [B=16, E=64, S=32768] float32
//   indices: [B=16, E=64] int (values in [0, S/STEP))
//   out:     [B, 1, S] float32  -> flat B*S
// out[b,s] = sum_e x[b, e, s - idx[b,e]*STEP]  where idx*STEP <= s
constexpr int B = 16;
constexpr int E = 64;
constexpr int S = 32768;
constexpr int STEP = 256;
constexpr int HALF = 1024;     // samples per half-tile (was 512)
constexpr int NH   = S / HALF; // 32 half-tiles
constexpr int GRP  = 16;       // loads in flight per thread

// Plain clang ext-vector — __builtin_nontemporal_* requires a pointer to
// scalar or vector-of-scalar, not HIP_vector_type.
typedef float f4 __attribute__((ext_vector_type(4)));

// Load-balanced gather, v3: larger contiguous segments per event.
//
// Round-1 post-mortem: cutting the instruction stream ~40% (event
// compaction) was perf-neutral -> kernel is HBM-bound, not issue-bound,
// at ~4.2 TB/s of the 6.3 TB/s ceiling. Remaining theory: 2 KB
// contiguous segments per (event, half-tile) under-utilize DRAM paging.
// This version doubles the segment to 4 KB: HALF=1024, 512-thread
// blocks. Waves 0-3 (threads 0..255) cover half-tile pr; waves 4-7
// cover 31-pr (pairing keeps per-block HBM demand ~constant). Grid
// (16,16) = 256 blocks = 1 block/CU, 8 waves = 2 waves/SIMD (same
// occupancy as before). Streaming loads/store are nontemporal (zero
// reuse).
__global__ __launch_bounds__(512)
void sparse_audio_gather(const float* __restrict__ x,
                         const int* __restrict__ idx,
                         float* __restrict__ out) {
    const int b     = blockIdx.y;
    const int pr    = blockIdx.x;                       // 0..15
    const int hs    = (int)(threadIdx.x >> 8);          // 0: half pr, 1: half 31-pr
    const int half  = hs ? (NH - 1 - pr) : pr;
    const int local = (int)(threadIdx.x & 255);
    const int s0    = half * HALF + local * 4;          // <= S-4 always

    // Compacted per-half lists: (te, e*S) pairs + padded count.
    __shared__ int2 lst[2][E + GRP];
    __shared__ int  cnt_l[2];

    // Threads 0..63 build the list for half pr, 64..127 for half 31-pr.
    if (threadIdx.x < 2 * E) {
        const int hsel = (int)(threadIdx.x >> 6);       // 0 or 1
        const int h    = hsel ? (NH - 1 - pr) : pr;
        const int lane = (int)(threadIdx.x & 63);
        const int te   = idx[b * E + lane] * STEP;
        const int smax = h * HALF + (HALF - 4);         // max s0 in this half
        const bool act = (te <= smax);
        const unsigned long long mask = __ballot(act);
        const int pos  = __popcll(mask & ((1ull << lane) - 1ull));
        const int cnt  = __popcll(mask);
        const int cntp = (cnt + GRP - 1) & ~(GRP - 1);  // pad to GRP multiple
        if (act) lst[hsel][pos] = make_int2(te, lane * S);
        // Sentinels: te huge -> off<0 on every lane -> m=0, clamped addr xb[0].
        if (lane >= cnt && lane < cntp) lst[hsel][lane] = make_int2(1 << 28, 0);
        if (lane == 0) cnt_l[hsel] = cntp;
    }
    __syncthreads();

    const float* xb  = x + (size_t)b * E * S;
    const int    cnt = cnt_l[hs];                       // wave-uniform, %GRP==0

    f4 acc = (f4)(0.f);

    // Unconditional clamped loads (address p.y + max(s0-te,0) is always in
    // [p.y, p.y + s0]), masked after the fact: GRP loads issue back-to-back
    // before any s_waitcnt -> 16 outstanding per thread.
    for (int i0 = 0; i0 < cnt; i0 += GRP) {
        int2 p[GRP];
        f4   v[GRP];
        float m[GRP];
        #pragma unroll
        for (int j = 0; j < GRP; ++j) p[j] = lst[hs][i0 + j];
        #pragma unroll
        for (int j = 0; j < GRP; ++j) {
            const int off  = s0 - p[j].x;
            const int offc = off < 0 ? 0 : off;
            m[j] = off < 0 ? 0.0f : 1.0f;
            v[j] = __builtin_nontemporal_load(
                       reinterpret_cast<const f4*>(
                           xb + (size_t)(p[j].y + offc)));
        }
        #pragma unroll
        for (int j = 0; j < GRP; ++j) {
            acc.x += m[j] * v[j].x;
            acc.y += m[j] * v[j].y;
            acc.z += m[j] * v[j].z;
            acc.w += m[j] * v[j].w;
        }
    }

    __builtin_nontemporal_store(acc,
        reinterpret_cast<f4*>(out + (size_t)b * S + s0));
}

extern "C" void kernel_launch(void* const* d_in, const int* in_sizes, int n_in,
                              void* d_out, int out_size, void* d_ws, size_t ws_size,
                              hipStream_t stream) {
    const float* x   = (const float*)d_in[0];
    const int*   idx = (const int*)d_in[1];
    float*       out = (float*)d_out;

    dim3 grid(S / (2 * HALF), B);   // (16, 16) — each block does 2 half-tiles
    dim3 block(512);
    sparse_audio_gather<<<grid, block, 0, stream>>>(x, idx, out);
}